// Round 9
// baseline (415.338 us; speedup 1.0000x reference)
//
#include <hip/hip_runtime.h>
#include <math.h>

// Problem constants: y is (8, 3, 256, 512) fp32, lmbd is (1,3).
#define TVW 512      // row length
#define TVC 3        // channels; channel = (row >> 8) % 3
#define RPB 64       // rows per block == lanes (one ROW PER LANE, no redundancy)
#define XSTR 513     // odd LDS row stride: row bases spread over all 32 banks

// Lane-per-row, fully predicated Condat state machine (round-1 idea, fixed):
//  - ONE instruction stream, no divergent 3-way branch: extend math is
//    branchless (r3/r4-validated), jump/terminate are exec-masked blocks that
//    cost ~1 issue each per iteration regardless of which lanes take them.
//  - Variable-length flushes -> per-lane WRITE CURSOR draining 1 elem/iter
//    IN PARALLEL with continued extends; a new jump merely stalls its lane
//    until its previous segment finishes draining.
//  - Jumps restart from register caches x[km+1],x[km+2],x[kp+1],x[kp+2]
//    (r5/r6-validated update rules) -> no dependent LDS gather on restart.
//  - x[k+3] speculative prefetch keeps the extend pipeline 2 iters ahead.
// In-place output in the LDS row (writes land strictly below every future
// read index; proven r0/r3/r4). 96 blocks x 64 threads; 131 KB LDS/block.
__global__ __launch_bounds__(64, 1)
void tv1d_lane2_kernel(const float* __restrict__ y,
                       const float* __restrict__ lmbd,
                       float* __restrict__ out,
                       int total_rows) {
    extern __shared__ float xs[];    // RPB * XSTR floats
    const int lane = threadIdx.x;    // block = one wave
    const int base_row = blockIdx.x * RPB;

    // ---- stage 64 rows; scalar: LDS banks consecutive per chunk (no conflict) ----
    {
        const float* src = y + (size_t)base_row * TVW;
        for (int e = lane; e < RPB * TVW; e += 64)
            xs[(e >> 9) * XSTR + (e & 511)] = src[e];
    }
    __syncthreads();

    {
        const int row = base_row + lane;
        float* x = xs + lane * XSTR;              // this lane's row (in-place)
        const float lam = log1pf(expf(lmbd[(row >> 8) % TVC]));
        const float nl = -lam, twol = 2.0f * lam;

        // Condat state (reference tuple) + register pipeline/caches
        int k = 0, k0 = 0, km = 0, kp = 0;
        float vmin = x[0] - lam, vmax = x[0] + lam;
        float umin = lam, umax = nl, denf = 1.0f;
        float yn = x[1], yn1 = x[2];              // x[k+1], x[k+2]
        float xkm1 = yn, xkm2 = yn1;              // x[km+1], x[km+2]
        float xkp1 = yn, xkp2 = yn1;              // x[kp+1], x[kp+2]
        int w = 0, wl = -1;                       // write cursor [w..wl]
        float wv = 0.0f;
        bool done = (row >= total_rows);

        for (int it = 0; it < 8192; ++it) {
            if (__ballot(!done || (w <= wl)) == 0ull) break;
            // speculative prefetch (consumed as yn1 two iterations out)
            const float ypre = x[k + 3 < TVW ? k + 3 : TVW - 1];
            // drain one cursor element (indices < k0 <= every future read)
            const bool fl = (w <= wl);
            if (fl) { x[w] = wv; ++w; }
            const bool busy = (w <= wl);

            const bool run = !done;
            const bool atEnd = (k == TVW - 1);
            const float umin_t = umin + yn - vmin;
            const float umax_t = umax + yn - vmax;
            const bool negc = run && (atEnd ? (umin < 0.0f) : (umin_t < nl));
            const bool posc = run && !negc && (atEnd ? (umax > 0.0f) : (umax_t > lam));
            const bool evt = negc || posc;
            const bool ext = run && !atEnd && !evt;        // extends even while draining
            const bool jmp = evt && !busy;                 // jumps wait for drain
            const bool trm = run && atEnd && !evt && !busy;

            if (ext) {                           // ---- b3 extend (branchless) ----
                const int kn = k + 1;
                denf += 1.0f;
                const float r = __builtin_amdgcn_rcpf(denf);
                const bool hm = (umin_t >= lam);
                const bool hp = (umax_t <= nl);
                vmin = fmaf(fmaxf(umin_t - lam, 0.0f), r, vmin);
                vmax = fmaf(fminf(umax_t + lam, 0.0f), r, vmax);
                umin = fminf(umin_t, lam);
                umax = fmaxf(umax_t, nl);
                if (hm) { km = kn; xkm1 = yn1; xkm2 = ypre; }
                if (hp) { kp = kn; xkp1 = yn1; xkp2 = ypre; }
                k = kn;
                yn = yn1; yn1 = ypre;
            } else if (jmp) {                    // ---- b1/b2/a1/a2 unified ----
                const int e = negc ? km : kp;
                wv = negc ? vmin : vmax;         // pre-restart value
                w = k0; wl = e < TVW - 1 ? e : TVW - 1;
                const int k0n = e + 1;
                const float newv = negc ? xkm1 : xkp1;   // x[min(k0n,  W-1)]
                const float nyn  = negc ? xkm2 : xkp2;   // x[min(k0n+1,W-1)]
                const float nyn1 = x[k0n + 2 < TVW ? k0n + 2 : TVW - 1];
                const bool bmid = !atEnd;
                const float ovmin = vmin, ovmax = vmax;
                vmin = negc ? newv : (bmid ? newv - twol : ovmin);
                vmax = posc ? newv : (bmid ? newv + twol : ovmax);
                umin = (posc && !bmid) ? (newv - lam - ovmin) : lam;   // a2 carry
                umax = (negc && !bmid) ? (newv + lam - ovmax) : nl;    // a1 carry
                if (negc || bmid) { km = k0n; xkm1 = nyn; xkm2 = nyn1; }
                if (posc || bmid) { kp = k0n; xkp1 = nyn; xkp2 = nyn1; }
                k = k0 = k0n; denf = 1.0f;
                yn = nyn; yn1 = nyn1;
            } else if (trm) {                    // ---- a3 terminate ----
                wv = vmin + umin * __builtin_amdgcn_rcpf(denf);
                w = k0; wl = TVW - 1;
                done = true;                     // cursor drains the tail
            }
            // else: stall (event waiting on drain) or idle — drain only
        }
    }
    __syncthreads();

    // ---- coalesced writeback (scalar; banks consecutive per chunk) ----
    {
        float* dst = out + (size_t)base_row * TVW;
        for (int e = lane; e < RPB * TVW; e += 64)
            dst[e] = xs[(e >> 9) * XSTR + (e & 511)];
    }
}

extern "C" void kernel_launch(void* const* d_in, const int* in_sizes, int n_in,
                              void* d_out, int out_size, void* d_ws, size_t ws_size,
                              hipStream_t stream) {
    const float* y    = (const float*)d_in[0];
    const float* lmbd = (const float*)d_in[1];
    float* out = (float*)d_out;

    const int total_rows = in_sizes[0] / TVW;              // 6144
    const int grid = (total_rows + RPB - 1) / RPB;         // 96 blocks (1 wave each)
    const size_t smem = (size_t)(RPB * XSTR) * sizeof(float);  // ~131 KB

    (void)hipFuncSetAttribute((const void*)tv1d_lane2_kernel,
                              hipFuncAttributeMaxDynamicSharedMemorySize,
                              (int)smem);
    tv1d_lane2_kernel<<<grid, 64, smem, stream>>>(y, lmbd, out, total_rows);
}